// Round 1
// baseline (1465.152 us; speedup 1.0000x reference)
//
#include <hip/hip_runtime.h>
#include <hip/hip_bf16.h>

#define T_TOK 4096
#define HDIM  1024
#define FDIM  4096
#define NEXP  8
#define CAP   4096

typedef __attribute__((ext_vector_type(8))) short short8;
typedef __attribute__((ext_vector_type(4))) float floatx4;
typedef __attribute__((ext_vector_type(4))) float float4v;
typedef __attribute__((ext_vector_type(4))) unsigned short ushort4v;

__device__ __forceinline__ unsigned short f2bf(float f) {
    union { float f; unsigned int u; } v; v.f = f;
    unsigned int u = v.u;
    u += 0x7fffu + ((u >> 16) & 1u);   // round-to-nearest-even
    return (unsigned short)(u >> 16);
}

__device__ __forceinline__ void gl2lds16(const void* g, void* l) {
    __builtin_amdgcn_global_load_lds(
        (const __attribute__((address_space(1))) unsigned int*)g,
        (__attribute__((address_space(3))) unsigned int*)l,
        16, 0, 0);
}

// ---------------- x fp32 -> bf16 ----------------
__global__ void k_convert_x(const float* __restrict__ x, unsigned short* __restrict__ xb) {
    int i = (blockIdx.x * 256 + threadIdx.x) * 4;
    float4v v = *(const float4v*)(x + i);
    ushort4v o = { f2bf(v[0]), f2bf(v[1]), f2bf(v[2]), f2bf(v[3]) };
    *(ushort4v*)(xb + i) = o;
}

// ---------------- transpose + cast: src [R][C] fp32 -> dst [C][R] bf16, batched over z ----------------
__global__ void k_transpose_cast(const float* __restrict__ src, unsigned short* __restrict__ dst,
                                 int R, int C) {
    __shared__ float tile[32][33];
    size_t base = (size_t)blockIdx.z * (size_t)R * (size_t)C;
    int c0 = blockIdx.x * 32, r0 = blockIdx.y * 32;
    int tx = threadIdx.x & 31, ty = threadIdx.x >> 5;  // ty: 0..7
#pragma unroll
    for (int i = 0; i < 32; i += 8)
        tile[ty + i][tx] = src[base + (size_t)(r0 + ty + i) * C + (c0 + tx)];
    __syncthreads();
#pragma unroll
    for (int i = 0; i < 32; i += 8)
        dst[base + (size_t)(c0 + ty + i) * R + (r0 + tx)] = f2bf(tile[tx][ty + i]);
}

// ---------------- router: logits, softmax, top-2, build per-expert lists ----------------
__global__ void k_router(const float* __restrict__ x, const float* __restrict__ wgate,
                         int* __restrict__ counts, int* __restrict__ ltok,
                         float* __restrict__ lwt) {
    int lane = threadIdx.x & 63;
    int tok = blockIdx.x * 4 + (threadIdx.x >> 6);
    const float* xr = x + (size_t)tok * HDIM;
    float acc[NEXP];
#pragma unroll
    for (int e = 0; e < NEXP; ++e) acc[e] = 0.f;
    for (int it = 0; it < HDIM / 256; ++it) {
        int h0 = it * 256 + lane * 4;
        float4v xv = *(const float4v*)(xr + h0);
#pragma unroll
        for (int j = 0; j < 4; ++j) {
            float4v w0 = *(const float4v*)(wgate + (size_t)(h0 + j) * NEXP);
            float4v w1 = *(const float4v*)(wgate + (size_t)(h0 + j) * NEXP + 4);
            float xs = xv[j];
            acc[0] += xs * w0[0]; acc[1] += xs * w0[1];
            acc[2] += xs * w0[2]; acc[3] += xs * w0[3];
            acc[4] += xs * w1[0]; acc[5] += xs * w1[1];
            acc[6] += xs * w1[2]; acc[7] += xs * w1[3];
        }
    }
#pragma unroll
    for (int off = 32; off >= 1; off >>= 1)
#pragma unroll
        for (int e = 0; e < NEXP; ++e)
            acc[e] += __shfl_xor(acc[e], off, 64);
    if (lane == 0) {
        float m = acc[0];
#pragma unroll
        for (int e = 1; e < NEXP; ++e) m = fmaxf(m, acc[e]);
        float p[NEXP], s = 0.f;
#pragma unroll
        for (int e = 0; e < NEXP; ++e) { p[e] = __expf(acc[e] - m); s += p[e]; }
        float inv = 1.f / s;
#pragma unroll
        for (int e = 0; e < NEXP; ++e) p[e] *= inv;
        int e0 = 0; float b0 = p[0];
#pragma unroll
        for (int e = 1; e < NEXP; ++e) if (p[e] > b0) { b0 = p[e]; e0 = e; }
        int e1 = -1; float b1 = -1.f;
#pragma unroll
        for (int e = 0; e < NEXP; ++e) if (e != e0 && p[e] > b1) { b1 = p[e]; e1 = e; }
        int p0 = atomicAdd(&counts[e0], 1);
        ltok[e0 * CAP + p0] = tok; lwt[e0 * CAP + p0] = b0;
        int p1 = atomicAdd(&counts[e1], 1);
        ltok[e1 * CAP + p1] = tok; lwt[e1 * CAP + p1] = b1;
    }
}

__global__ void k_prefix(const int* __restrict__ counts, int* __restrict__ offs) {
    if (threadIdx.x == 0) {
        int s = 0;
#pragma unroll
        for (int e = 0; e < NEXP; ++e) { offs[e] = s; s += counts[e]; }
    }
}

// ---------------- GEMM1: h = silu(x@Wg) * (x@Wu), gathered rows, fused gate+up ----------------
__global__ __launch_bounds__(256, 2)
void k_gemm1(const unsigned short* __restrict__ xb,    // [T][H] bf16
             const unsigned short* __restrict__ wgt,   // [E][F][H] bf16 (transposed)
             const unsigned short* __restrict__ wut,   // [E][F][H]
             const int* __restrict__ counts, const int* __restrict__ offs,
             const int* __restrict__ ltok,
             unsigned short* __restrict__ hbuf)        // [2T+128][F] bf16
{
    const int e = blockIdx.x >> 5;
    const int rowtile = blockIdx.x & 31;
    const int M = counts[e];
    if (rowtile * 128 >= M) return;
    const int ntile = blockIdx.y;

    __shared__ __align__(16) unsigned short lA[128 * 32];
    __shared__ __align__(16) unsigned short lBg[128 * 32];
    __shared__ __align__(16) unsigned short lBu[128 * 32];
    __shared__ int stok[128];

    const int t = threadIdx.x;
    const int wave = t >> 6, lane = t & 63;

    if (t < 128) {
        int i = rowtile * 128 + t;
        stok[t] = (i < M) ? ltok[e * CAP + i] : ltok[e * CAP];
    }
    __syncthreads();

    const int r0 = t >> 2, k8 = t & 3;          // chunk0: rows 0..63; chunk1: rows 64..127
    const unsigned short* pA0 = xb + (size_t)stok[r0] * HDIM + k8 * 8;
    const unsigned short* pA1 = xb + (size_t)stok[r0 + 64] * HDIM + k8 * 8;
    const size_t wbase = (size_t)e * FDIM * HDIM + (size_t)(ntile * 128) * HDIM;
    const unsigned short* pG0 = wgt + wbase + (size_t)r0 * HDIM + k8 * 8;
    const unsigned short* pG1 = wgt + wbase + (size_t)(r0 + 64) * HDIM + k8 * 8;
    const unsigned short* pU0 = wut + wbase + (size_t)r0 * HDIM + k8 * 8;
    const unsigned short* pU1 = wut + wbase + (size_t)(r0 + 64) * HDIM + k8 * 8;

    unsigned short* dA0 = &lA[(wave * 64) * 8];
    unsigned short* dA1 = &lA[(256 + wave * 64) * 8];
    unsigned short* dG0 = &lBg[(wave * 64) * 8];
    unsigned short* dG1 = &lBg[(256 + wave * 64) * 8];
    unsigned short* dU0 = &lBu[(wave * 64) * 8];
    unsigned short* dU1 = &lBu[(256 + wave * 64) * 8];

    const int wm = wave >> 1, wn = wave & 1;
    const int fr = lane & 15, kg = lane >> 4;

    floatx4 accg[4][4], accu[4][4];
#pragma unroll
    for (int mi = 0; mi < 4; ++mi)
#pragma unroll
        for (int ni = 0; ni < 4; ++ni) {
            floatx4 z = {0.f, 0.f, 0.f, 0.f};
            accg[mi][ni] = z; accu[mi][ni] = z;
        }

    for (int ks = 0; ks < HDIM / 32; ++ks) {
        gl2lds16(pA0, dA0); gl2lds16(pA1, dA1);
        gl2lds16(pG0, dG0); gl2lds16(pG1, dG1);
        gl2lds16(pU0, dU0); gl2lds16(pU1, dU1);
        pA0 += 32; pA1 += 32; pG0 += 32; pG1 += 32; pU0 += 32; pU1 += 32;
        __syncthreads();
        short8 a[4], bg[4], bu[4];
#pragma unroll
        for (int mi = 0; mi < 4; ++mi)
            a[mi] = *(const short8*)&lA[(wm * 64 + mi * 16 + fr) * 32 + kg * 8];
#pragma unroll
        for (int ni = 0; ni < 4; ++ni) {
            bg[ni] = *(const short8*)&lBg[(wn * 64 + ni * 16 + fr) * 32 + kg * 8];
            bu[ni] = *(const short8*)&lBu[(wn * 64 + ni * 16 + fr) * 32 + kg * 8];
        }
#pragma unroll
        for (int mi = 0; mi < 4; ++mi)
#pragma unroll
            for (int ni = 0; ni < 4; ++ni) {
                accg[mi][ni] = __builtin_amdgcn_mfma_f32_16x16x32_bf16(a[mi], bg[ni], accg[mi][ni], 0, 0, 0);
                accu[mi][ni] = __builtin_amdgcn_mfma_f32_16x16x32_bf16(a[mi], bu[ni], accu[mi][ni], 0, 0, 0);
            }
        __syncthreads();
    }

    const int hrow0 = offs[e] + rowtile * 128;
#pragma unroll
    for (int mi = 0; mi < 4; ++mi)
#pragma unroll
        for (int ni = 0; ni < 4; ++ni) {
            int c = ntile * 128 + wn * 64 + ni * 16 + fr;
#pragma unroll
            for (int r = 0; r < 4; ++r) {
                int rr = wm * 64 + mi * 16 + kg * 4 + r;
                if (rowtile * 128 + rr < M) {
                    float g = accg[mi][ni][r];
                    float val = (g / (1.f + __expf(-g))) * accu[mi][ni][r];
                    hbuf[(size_t)(hrow0 + rr) * FDIM + c] = f2bf(val);
                }
            }
        }
}

// ---------------- GEMM2: out[tok] += w * (h @ Wd^T) ----------------
__global__ __launch_bounds__(256, 2)
void k_gemm2(const unsigned short* __restrict__ hbuf,  // [2T+128][F] bf16
             const unsigned short* __restrict__ wdt,   // [E][H][F] bf16 (transposed)
             const int* __restrict__ counts, const int* __restrict__ offs,
             const int* __restrict__ ltok, const float* __restrict__ lwt,
             float* __restrict__ out)                  // [T][H] fp32 (zeroed)
{
    const int e = blockIdx.x >> 5;
    const int rowtile = blockIdx.x & 31;
    const int M = counts[e];
    if (rowtile * 128 >= M) return;
    const int ntile = blockIdx.y;  // 0..7

    __shared__ __align__(16) unsigned short lA[128 * 32];
    __shared__ __align__(16) unsigned short lB[128 * 32];
    __shared__ int stok[128];
    __shared__ float swt[128];

    const int t = threadIdx.x;
    const int wave = t >> 6, lane = t & 63;

    if (t < 128) {
        int i = rowtile * 128 + t;
        if (i < M) { stok[t] = ltok[e * CAP + i]; swt[t] = lwt[e * CAP + i]; }
        else       { stok[t] = 0; swt[t] = 0.f; }
    }

    const int row0 = offs[e] + rowtile * 128;
    const int r0 = t >> 2, k8 = t & 3;
    const unsigned short* pA0 = hbuf + (size_t)(row0 + r0) * FDIM + k8 * 8;
    const unsigned short* pA1 = hbuf + (size_t)(row0 + 64 + r0) * FDIM + k8 * 8;
    const size_t wb = (size_t)e * HDIM * FDIM + (size_t)(ntile * 128) * FDIM;
    const unsigned short* pB0 = wdt + wb + (size_t)r0 * FDIM + k8 * 8;
    const unsigned short* pB1 = wdt + wb + (size_t)(64 + r0) * FDIM + k8 * 8;

    unsigned short* dA0 = &lA[(wave * 64) * 8];
    unsigned short* dA1 = &lA[(256 + wave * 64) * 8];
    unsigned short* dB0 = &lB[(wave * 64) * 8];
    unsigned short* dB1 = &lB[(256 + wave * 64) * 8];

    const int wm = wave >> 1, wn = wave & 1;
    const int fr = lane & 15, kg = lane >> 4;

    floatx4 acc[4][4];
#pragma unroll
    for (int mi = 0; mi < 4; ++mi)
#pragma unroll
        for (int ni = 0; ni < 4; ++ni) {
            floatx4 z = {0.f, 0.f, 0.f, 0.f};
            acc[mi][ni] = z;
        }

    for (int ks = 0; ks < FDIM / 32; ++ks) {
        gl2lds16(pA0, dA0); gl2lds16(pA1, dA1);
        gl2lds16(pB0, dB0); gl2lds16(pB1, dB1);
        pA0 += 32; pA1 += 32; pB0 += 32; pB1 += 32;
        __syncthreads();
        short8 a[4], b[4];
#pragma unroll
        for (int mi = 0; mi < 4; ++mi)
            a[mi] = *(const short8*)&lA[(wm * 64 + mi * 16 + fr) * 32 + kg * 8];
#pragma unroll
        for (int ni = 0; ni < 4; ++ni)
            b[ni] = *(const short8*)&lB[(wn * 64 + ni * 16 + fr) * 32 + kg * 8];
#pragma unroll
        for (int mi = 0; mi < 4; ++mi)
#pragma unroll
            for (int ni = 0; ni < 4; ++ni)
                acc[mi][ni] = __builtin_amdgcn_mfma_f32_16x16x32_bf16(a[mi], b[ni], acc[mi][ni], 0, 0, 0);
        __syncthreads();
    }

#pragma unroll
    for (int mi = 0; mi < 4; ++mi)
#pragma unroll
        for (int ni = 0; ni < 4; ++ni) {
            int c = ntile * 128 + wn * 64 + ni * 16 + fr;
#pragma unroll
            for (int r = 0; r < 4; ++r) {
                int rr = wm * 64 + mi * 16 + kg * 4 + r;
                if (rowtile * 128 + rr < M) {
                    float val = acc[mi][ni][r] * swt[rr];
                    atomicAdd(&out[(size_t)stok[rr] * HDIM + c], val);
                }
            }
        }
}

extern "C" void kernel_launch(void* const* d_in, const int* in_sizes, int n_in,
                              void* d_out, int out_size, void* d_ws, size_t ws_size,
                              hipStream_t stream) {
    const float* x     = (const float*)d_in[0];  // [4096][1024]
    const float* wgate = (const float*)d_in[1];  // [1024][8]
    const float* wg    = (const float*)d_in[2];  // [8][1024][4096]
    const float* wu    = (const float*)d_in[3];  // [8][1024][4096]
    const float* wd    = (const float*)d_in[4];  // [8][4096][1024]
    float* out = (float*)d_out;

    char* ws = (char*)d_ws;
    size_t off = 0;
    unsigned short* xb  = (unsigned short*)(ws + off); off += (size_t)T_TOK * HDIM * 2;
    unsigned short* wgt = (unsigned short*)(ws + off); off += (size_t)NEXP * FDIM * HDIM * 2;
    unsigned short* wut = (unsigned short*)(ws + off); off += (size_t)NEXP * FDIM * HDIM * 2;
    unsigned short* wdt = (unsigned short*)(ws + off); off += (size_t)NEXP * HDIM * FDIM * 2;
    unsigned short* hbuf= (unsigned short*)(ws + off); off += (size_t)(2 * T_TOK + 128) * FDIM * 2;
    int*   ltok   = (int*)(ws + off);   off += (size_t)NEXP * CAP * 4;
    float* lwt    = (float*)(ws + off); off += (size_t)NEXP * CAP * 4;
    int*   counts = (int*)(ws + off);   off += 256;
    int*   offs   = (int*)(ws + off);   off += 256;

    hipMemsetAsync(counts, 0, 32, stream);
    hipMemsetAsync(out, 0, (size_t)T_TOK * HDIM * 4, stream);

    k_convert_x<<<T_TOK * HDIM / 1024, 256, 0, stream>>>(x, xb);
    k_transpose_cast<<<dim3(FDIM / 32, HDIM / 32, NEXP), 256, 0, stream>>>(wg, wgt, HDIM, FDIM);
    k_transpose_cast<<<dim3(FDIM / 32, HDIM / 32, NEXP), 256, 0, stream>>>(wu, wut, HDIM, FDIM);
    k_transpose_cast<<<dim3(HDIM / 32, FDIM / 32, NEXP), 256, 0, stream>>>(wd, wdt, FDIM, HDIM);
    k_router<<<T_TOK / 4, 256, 0, stream>>>(x, wgate, counts, ltok, lwt);
    k_prefix<<<1, 64, 0, stream>>>(counts, offs);
    k_gemm1<<<dim3(NEXP * 32, FDIM / 128), 256, 0, stream>>>(xb, wgt, wut, counts, offs, ltok, hbuf);
    k_gemm2<<<dim3(NEXP * 32, HDIM / 128), 256, 0, stream>>>(hbuf, wdt, counts, offs, ltok, lwt, out);
}

// Round 2
// 846.480 us; speedup vs baseline: 1.7309x; 1.7309x over previous
//
#include <hip/hip_runtime.h>
#include <hip/hip_bf16.h>

#define T_TOK 4096
#define HDIM  1024
#define FDIM  4096
#define NEXP  8
#define CAP   4096
#define MAXWL 128

typedef __attribute__((ext_vector_type(8))) short short8;
typedef __attribute__((ext_vector_type(4))) float floatx4;
typedef __attribute__((ext_vector_type(4))) float float4v;
typedef __attribute__((ext_vector_type(4))) unsigned short ushort4v;

__device__ __forceinline__ unsigned short f2bf(float f) {
    union { float f; unsigned int u; } v; v.f = f;
    unsigned int u = v.u;
    u += 0x7fffu + ((u >> 16) & 1u);   // round-to-nearest-even
    return (unsigned short)(u >> 16);
}

__device__ __forceinline__ void gl2lds16(const void* g, void* l) {
    __builtin_amdgcn_global_load_lds(
        (const __attribute__((address_space(1))) unsigned int*)g,
        (__attribute__((address_space(3))) unsigned int*)l,
        16, 0, 0);
}

// ---------------- x fp32 -> bf16 ----------------
__global__ void k_convert_x(const float* __restrict__ x, unsigned short* __restrict__ xb) {
    int i = (blockIdx.x * 256 + threadIdx.x) * 4;
    float4v v = *(const float4v*)(x + i);
    ushort4v o = { f2bf(v[0]), f2bf(v[1]), f2bf(v[2]), f2bf(v[3]) };
    *(ushort4v*)(xb + i) = o;
}

// ---------------- transpose + cast: src [R][C] fp32 -> dst [C][R] bf16, 64x64 tiles ----------------
__global__ void k_transpose_cast(const float* __restrict__ src, unsigned short* __restrict__ dst,
                                 int R, int C) {
    __shared__ float tile[64][65];
    size_t base = (size_t)blockIdx.z * (size_t)R * (size_t)C;
    int c0 = blockIdx.x * 64, r0 = blockIdx.y * 64;
    int lx = threadIdx.x & 15, ly = threadIdx.x >> 4;  // lx: float4 col, ly: 0..15
#pragma unroll
    for (int i = 0; i < 4; ++i) {
        int rr = i * 16 + ly;
        float4v v = *(const float4v*)(src + base + (size_t)(r0 + rr) * C + c0 + lx * 4);
        tile[rr][lx * 4 + 0] = v[0]; tile[rr][lx * 4 + 1] = v[1];
        tile[rr][lx * 4 + 2] = v[2]; tile[rr][lx * 4 + 3] = v[3];
    }
    __syncthreads();
#pragma unroll
    for (int i = 0; i < 4; ++i) {
        int cc = i * 16 + ly;
        ushort4v o = { f2bf(tile[lx * 4 + 0][cc]), f2bf(tile[lx * 4 + 1][cc]),
                       f2bf(tile[lx * 4 + 2][cc]), f2bf(tile[lx * 4 + 3][cc]) };
        *(ushort4v*)(dst + base + (size_t)(c0 + cc) * R + r0 + lx * 4) = o;
    }
}

// ---------------- router: logits, softmax, top-2, per-expert lists ----------------
__global__ void k_router(const float* __restrict__ x, const float* __restrict__ wgate,
                         int* __restrict__ counts, int* __restrict__ ltok,
                         float* __restrict__ lwt) {
    int lane = threadIdx.x & 63;
    int tok = blockIdx.x * 4 + (threadIdx.x >> 6);
    const float* xr = x + (size_t)tok * HDIM;
    float acc[NEXP];
#pragma unroll
    for (int e = 0; e < NEXP; ++e) acc[e] = 0.f;
    for (int it = 0; it < HDIM / 256; ++it) {
        int h0 = it * 256 + lane * 4;
        float4v xv = *(const float4v*)(xr + h0);
#pragma unroll
        for (int j = 0; j < 4; ++j) {
            float4v w0 = *(const float4v*)(wgate + (size_t)(h0 + j) * NEXP);
            float4v w1 = *(const float4v*)(wgate + (size_t)(h0 + j) * NEXP + 4);
            float xs = xv[j];
            acc[0] += xs * w0[0]; acc[1] += xs * w0[1];
            acc[2] += xs * w0[2]; acc[3] += xs * w0[3];
            acc[4] += xs * w1[0]; acc[5] += xs * w1[1];
            acc[6] += xs * w1[2]; acc[7] += xs * w1[3];
        }
    }
#pragma unroll
    for (int off = 32; off >= 1; off >>= 1)
#pragma unroll
        for (int e = 0; e < NEXP; ++e)
            acc[e] += __shfl_xor(acc[e], off, 64);
    if (lane == 0) {
        float m = acc[0];
#pragma unroll
        for (int e = 1; e < NEXP; ++e) m = fmaxf(m, acc[e]);
        float p[NEXP], s = 0.f;
#pragma unroll
        for (int e = 0; e < NEXP; ++e) { p[e] = __expf(acc[e] - m); s += p[e]; }
        float inv = 1.f / s;
#pragma unroll
        for (int e = 0; e < NEXP; ++e) p[e] *= inv;
        int e0 = 0; float b0 = p[0];
#pragma unroll
        for (int e = 1; e < NEXP; ++e) if (p[e] > b0) { b0 = p[e]; e0 = e; }
        int e1 = -1; float b1 = -1.f;
#pragma unroll
        for (int e = 0; e < NEXP; ++e) if (e != e0 && p[e] > b1) { b1 = p[e]; e1 = e; }
        int p0 = atomicAdd(&counts[e0], 1);
        ltok[e0 * CAP + p0] = tok; lwt[e0 * CAP + p0] = b0;
        int p1 = atomicAdd(&counts[e1], 1);
        ltok[e1 * CAP + p1] = tok; lwt[e1 * CAP + p1] = b1;
    }
}

// prefix sums + compact (expert, rowtile) worklist. Sum of counts == 8192 so nwl <= 71.
__global__ void k_prefix(const int* __restrict__ counts, int* __restrict__ offs,
                         int* __restrict__ wl, int* __restrict__ nwl) {
    if (threadIdx.x == 0) {
        int s = 0;
#pragma unroll
        for (int e = 0; e < NEXP; ++e) { offs[e] = s; s += counts[e]; }
        int n = 0;
        for (int e = 0; e < NEXP; ++e)
            for (int r = 0; r * 128 < counts[e] && n < MAXWL; ++r)
                wl[n++] = (e << 8) | r;
        nwl[0] = n;
    }
}

// ---------------- GEMM1: h = silu(x@Wg) * (x@Wu), 128 rows x 64 cols per matrix ----------------
__global__ __launch_bounds__(256, 2)
void k_gemm1(const unsigned short* __restrict__ xb,    // [T][H] bf16
             const unsigned short* __restrict__ wgt,   // [E][F][H] bf16
             const unsigned short* __restrict__ wut,   // [E][F][H]
             const int* __restrict__ counts, const int* __restrict__ offs,
             const int* __restrict__ ltok,
             const int* __restrict__ wl, const int* __restrict__ nwl,
             unsigned short* __restrict__ hbuf)        // [2T+128][F] bf16
{
    if ((int)blockIdx.y >= nwl[0]) return;
    const int w = wl[blockIdx.y];
    const int e = w >> 8, rowtile = w & 255;
    const int M = counts[e];
    const int ftile = blockIdx.x;  // 0..63 (64 f-cols per block)

    __shared__ __align__(16) unsigned short lA[128 * 32];   // 8 KB
    __shared__ __align__(16) unsigned short lBg[64 * 32];   // 4 KB
    __shared__ __align__(16) unsigned short lBu[64 * 32];   // 4 KB
    __shared__ int stok[128];

    const int t = threadIdx.x;
    const int wave = t >> 6, lane = t & 63;

    if (t < 128) {
        int i = rowtile * 128 + t;
        stok[t] = (i < M) ? ltok[e * CAP + i] : ltok[e * CAP];
    }
    __syncthreads();

    const int r0 = t >> 2, k8 = t & 3;
    const unsigned short* pA0 = xb + (size_t)stok[r0] * HDIM + k8 * 8;
    const unsigned short* pA1 = xb + (size_t)stok[r0 + 64] * HDIM + k8 * 8;
    const size_t wbase = (size_t)e * FDIM * HDIM + (size_t)(ftile * 64) * HDIM;
    const unsigned short* pG0 = wgt + wbase + (size_t)r0 * HDIM + k8 * 8;
    const unsigned short* pU0 = wut + wbase + (size_t)r0 * HDIM + k8 * 8;

    unsigned short* dA0 = &lA[wave * 512];
    unsigned short* dA1 = &lA[2048 + wave * 512];
    unsigned short* dG0 = &lBg[wave * 512];
    unsigned short* dU0 = &lBu[wave * 512];

    const int wm = wave >> 1, wn = wave & 1;
    const int fr = lane & 15, kg = lane >> 4;

    floatx4 accg[4][2], accu[4][2];
#pragma unroll
    for (int mi = 0; mi < 4; ++mi)
#pragma unroll
        for (int ni = 0; ni < 2; ++ni) {
            floatx4 z = {0.f, 0.f, 0.f, 0.f};
            accg[mi][ni] = z; accu[mi][ni] = z;
        }

    for (int ks = 0; ks < HDIM / 32; ++ks) {
        gl2lds16(pA0, dA0); gl2lds16(pA1, dA1);
        gl2lds16(pG0, dG0); gl2lds16(pU0, dU0);
        pA0 += 32; pA1 += 32; pG0 += 32; pU0 += 32;
        __syncthreads();
        short8 a[4], bg[2], bu[2];
#pragma unroll
        for (int mi = 0; mi < 4; ++mi)
            a[mi] = *(const short8*)&lA[(wm * 64 + mi * 16 + fr) * 32 + kg * 8];
#pragma unroll
        for (int ni = 0; ni < 2; ++ni) {
            bg[ni] = *(const short8*)&lBg[(wn * 32 + ni * 16 + fr) * 32 + kg * 8];
            bu[ni] = *(const short8*)&lBu[(wn * 32 + ni * 16 + fr) * 32 + kg * 8];
        }
#pragma unroll
        for (int mi = 0; mi < 4; ++mi)
#pragma unroll
            for (int ni = 0; ni < 2; ++ni) {
                accg[mi][ni] = __builtin_amdgcn_mfma_f32_16x16x32_bf16(a[mi], bg[ni], accg[mi][ni], 0, 0, 0);
                accu[mi][ni] = __builtin_amdgcn_mfma_f32_16x16x32_bf16(a[mi], bu[ni], accu[mi][ni], 0, 0, 0);
            }
        __syncthreads();
    }

    const int hrow0 = offs[e] + rowtile * 128;
#pragma unroll
    for (int mi = 0; mi < 4; ++mi)
#pragma unroll
        for (int ni = 0; ni < 2; ++ni) {
            int c = ftile * 64 + wn * 32 + ni * 16 + fr;
#pragma unroll
            for (int r = 0; r < 4; ++r) {
                int rr = wm * 64 + mi * 16 + kg * 4 + r;
                if (rowtile * 128 + rr < M) {
                    float g = accg[mi][ni][r];
                    float val = (g / (1.f + __expf(-g))) * accu[mi][ni][r];
                    hbuf[(size_t)(hrow0 + rr) * FDIM + c] = f2bf(val);
                }
            }
        }
}

// ---------------- GEMM2: out[tok] += w * (h @ Wd^T), split-K=2 ----------------
__global__ __launch_bounds__(256, 2)
void k_gemm2(const unsigned short* __restrict__ hbuf,  // [2T+128][F] bf16
             const unsigned short* __restrict__ wdt,   // [E][H][F] bf16
             const int* __restrict__ counts, const int* __restrict__ offs,
             const int* __restrict__ ltok, const float* __restrict__ lwt,
             const int* __restrict__ wl, const int* __restrict__ nwl,
             float* __restrict__ out)                  // [T][H] fp32 (zeroed)
{
    if ((int)blockIdx.y >= nwl[0]) return;
    const int w = wl[blockIdx.y];
    const int e = w >> 8, rowtile = w & 255;
    const int M = counts[e];
    const int htile = blockIdx.x;  // 0..7
    const int khalf = blockIdx.z;  // 0..1

    __shared__ __align__(16) unsigned short lA[128 * 32];
    __shared__ __align__(16) unsigned short lB[128 * 32];
    __shared__ int stok[128];
    __shared__ float swt[128];

    const int t = threadIdx.x;
    const int wave = t >> 6, lane = t & 63;

    if (t < 128) {
        int i = rowtile * 128 + t;
        if (i < M) { stok[t] = ltok[e * CAP + i]; swt[t] = lwt[e * CAP + i]; }
        else       { stok[t] = 0; swt[t] = 0.f; }
    }

    const int row0 = offs[e] + rowtile * 128;
    const int r0 = t >> 2, k8 = t & 3;
    const int kofs = khalf * (FDIM / 2);
    const unsigned short* pA0 = hbuf + (size_t)(row0 + r0) * FDIM + kofs + k8 * 8;
    const unsigned short* pA1 = hbuf + (size_t)(row0 + 64 + r0) * FDIM + kofs + k8 * 8;
    const size_t wb = (size_t)e * HDIM * FDIM + (size_t)(htile * 128) * FDIM;
    const unsigned short* pB0 = wdt + wb + (size_t)r0 * FDIM + kofs + k8 * 8;
    const unsigned short* pB1 = wdt + wb + (size_t)(64 + r0) * FDIM + kofs + k8 * 8;

    unsigned short* dA0 = &lA[wave * 512];
    unsigned short* dA1 = &lA[2048 + wave * 512];
    unsigned short* dB0 = &lB[wave * 512];
    unsigned short* dB1 = &lB[2048 + wave * 512];

    const int wm = wave >> 1, wn = wave & 1;
    const int fr = lane & 15, kg = lane >> 4;

    floatx4 acc[4][4];
#pragma unroll
    for (int mi = 0; mi < 4; ++mi)
#pragma unroll
        for (int ni = 0; ni < 4; ++ni) {
            floatx4 z = {0.f, 0.f, 0.f, 0.f};
            acc[mi][ni] = z;
        }

    for (int ks = 0; ks < FDIM / 64; ++ks) {   // 64 steps of BK=32 over this K-half
        gl2lds16(pA0, dA0); gl2lds16(pA1, dA1);
        gl2lds16(pB0, dB0); gl2lds16(pB1, dB1);
        pA0 += 32; pA1 += 32; pB0 += 32; pB1 += 32;
        __syncthreads();
        short8 a[4], b[4];
#pragma unroll
        for (int mi = 0; mi < 4; ++mi)
            a[mi] = *(const short8*)&lA[(wm * 64 + mi * 16 + fr) * 32 + kg * 8];
#pragma unroll
        for (int ni = 0; ni < 4; ++ni)
            b[ni] = *(const short8*)&lB[(wn * 64 + ni * 16 + fr) * 32 + kg * 8];
#pragma unroll
        for (int mi = 0; mi < 4; ++mi)
#pragma unroll
            for (int ni = 0; ni < 4; ++ni)
                acc[mi][ni] = __builtin_amdgcn_mfma_f32_16x16x32_bf16(a[mi], b[ni], acc[mi][ni], 0, 0, 0);
        __syncthreads();
    }

#pragma unroll
    for (int mi = 0; mi < 4; ++mi)
#pragma unroll
        for (int ni = 0; ni < 4; ++ni) {
            int c = htile * 128 + wn * 64 + ni * 16 + fr;
#pragma unroll
            for (int r = 0; r < 4; ++r) {
                int rr = wm * 64 + mi * 16 + kg * 4 + r;
                if (rowtile * 128 + rr < M) {
                    float val = acc[mi][ni][r] * swt[rr];
                    atomicAdd(&out[(size_t)stok[rr] * HDIM + c], val);
                }
            }
        }
}

extern "C" void kernel_launch(void* const* d_in, const int* in_sizes, int n_in,
                              void* d_out, int out_size, void* d_ws, size_t ws_size,
                              hipStream_t stream) {
    const float* x     = (const float*)d_in[0];  // [4096][1024]
    const float* wgate = (const float*)d_in[1];  // [1024][8]
    const float* wg    = (const float*)d_in[2];  // [8][1024][4096]
    const float* wu    = (const float*)d_in[3];  // [8][1024][4096]
    const float* wd    = (const float*)d_in[4];  // [8][4096][1024]
    float* out = (float*)d_out;

    char* ws = (char*)d_ws;
    size_t off = 0;
    unsigned short* xb  = (unsigned short*)(ws + off); off += (size_t)T_TOK * HDIM * 2;
    unsigned short* wgt = (unsigned short*)(ws + off); off += (size_t)NEXP * FDIM * HDIM * 2;
    unsigned short* wut = (unsigned short*)(ws + off); off += (size_t)NEXP * FDIM * HDIM * 2;
    unsigned short* wdt = (unsigned short*)(ws + off); off += (size_t)NEXP * HDIM * FDIM * 2;
    unsigned short* hbuf= (unsigned short*)(ws + off); off += (size_t)(2 * T_TOK + 128) * FDIM * 2;
    int*   ltok   = (int*)(ws + off);   off += (size_t)NEXP * CAP * 4;
    float* lwt    = (float*)(ws + off); off += (size_t)NEXP * CAP * 4;
    int*   counts = (int*)(ws + off);   off += 256;
    int*   offs   = (int*)(ws + off);   off += 256;
    int*   wl     = (int*)(ws + off);   off += MAXWL * 4;
    int*   nwl    = (int*)(ws + off);   off += 256;

    hipMemsetAsync(counts, 0, 32, stream);
    hipMemsetAsync(out, 0, (size_t)T_TOK * HDIM * 4, stream);

    k_convert_x<<<T_TOK * HDIM / 1024, 256, 0, stream>>>(x, xb);
    k_transpose_cast<<<dim3(FDIM / 64, HDIM / 64, NEXP), 256, 0, stream>>>(wg, wgt, HDIM, FDIM);
    k_transpose_cast<<<dim3(FDIM / 64, HDIM / 64, NEXP), 256, 0, stream>>>(wu, wut, HDIM, FDIM);
    k_transpose_cast<<<dim3(HDIM / 64, FDIM / 64, NEXP), 256, 0, stream>>>(wd, wdt, FDIM, HDIM);
    k_router<<<T_TOK / 4, 256, 0, stream>>>(x, wgate, counts, ltok, lwt);
    k_prefix<<<1, 64, 0, stream>>>(counts, offs, wl, nwl);
    k_gemm1<<<dim3(FDIM / 64, 72), 256, 0, stream>>>(xb, wgt, wut, counts, offs, ltok, wl, nwl, hbuf);
    k_gemm2<<<dim3(HDIM / 128, 72, 2), 256, 0, stream>>>(hbuf, wdt, counts, offs, ltok, lwt, wl, nwl, out);
}

// Round 3
// 828.749 us; speedup vs baseline: 1.7679x; 1.0214x over previous
//
#include <hip/hip_runtime.h>
#include <hip/hip_bf16.h>

#define T_TOK 4096
#define HDIM  1024
#define FDIM  4096
#define NEXP  8
#define CAP   4096
#define MAXWL 128
#define OBR   (2 * T_TOK + 128)   // compact rows incl. padding

typedef __attribute__((ext_vector_type(8))) short short8;
typedef __attribute__((ext_vector_type(4))) float floatx4;
typedef __attribute__((ext_vector_type(4))) float float4v;
typedef __attribute__((ext_vector_type(4))) unsigned short ushort4v;

__device__ __forceinline__ unsigned short f2bf(float f) {
    union { float f; unsigned int u; } v; v.f = f;
    unsigned int u = v.u;
    u += 0x7fffu + ((u >> 16) & 1u);   // round-to-nearest-even
    return (unsigned short)(u >> 16);
}

__device__ __forceinline__ void gl2lds16(const void* g, void* l) {
    __builtin_amdgcn_global_load_lds(
        (const __attribute__((address_space(1))) unsigned int*)g,
        (__attribute__((address_space(3))) unsigned int*)l,
        16, 0, 0);
}

// ---------------- transpose + cast: src [R][C] fp32 -> dst [C][R] bf16, 64x64 tiles ----------------
__global__ void k_transpose_cast(const float* __restrict__ src, unsigned short* __restrict__ dst,
                                 int R, int C) {
    __shared__ float tile[64][65];
    size_t base = (size_t)blockIdx.z * (size_t)R * (size_t)C;
    int c0 = blockIdx.x * 64, r0 = blockIdx.y * 64;
    int lx = threadIdx.x & 15, ly = threadIdx.x >> 4;  // lx: float4 col, ly: 0..15
#pragma unroll
    for (int i = 0; i < 4; ++i) {
        int rr = i * 16 + ly;
        float4v v = *(const float4v*)(src + base + (size_t)(r0 + rr) * C + c0 + lx * 4);
        tile[rr][lx * 4 + 0] = v[0]; tile[rr][lx * 4 + 1] = v[1];
        tile[rr][lx * 4 + 2] = v[2]; tile[rr][lx * 4 + 3] = v[3];
    }
    __syncthreads();
#pragma unroll
    for (int i = 0; i < 4; ++i) {
        int cc = i * 16 + ly;
        ushort4v o = { f2bf(tile[lx * 4 + 0][cc]), f2bf(tile[lx * 4 + 1][cc]),
                       f2bf(tile[lx * 4 + 2][cc]), f2bf(tile[lx * 4 + 3][cc]) };
        *(ushort4v*)(dst + base + (size_t)(c0 + cc) * R + r0 + lx * 4) = o;
    }
}

// ---------------- router (+ x cast): logits, softmax, top-2, lists, per-token slots ----------------
__global__ void k_router(const float* __restrict__ x, const float* __restrict__ wgate,
                         unsigned short* __restrict__ xb,
                         int* __restrict__ counts, int* __restrict__ ltok,
                         float* __restrict__ lwt, int* __restrict__ tslot) {
    int lane = threadIdx.x & 63;
    int tok = blockIdx.x * 4 + (threadIdx.x >> 6);
    const float* xr = x + (size_t)tok * HDIM;
    unsigned short* xbr = xb + (size_t)tok * HDIM;
    float acc[NEXP];
#pragma unroll
    for (int e = 0; e < NEXP; ++e) acc[e] = 0.f;
    for (int it = 0; it < HDIM / 256; ++it) {
        int h0 = it * 256 + lane * 4;
        float4v xv = *(const float4v*)(xr + h0);
        ushort4v xo = { f2bf(xv[0]), f2bf(xv[1]), f2bf(xv[2]), f2bf(xv[3]) };
        *(ushort4v*)(xbr + h0) = xo;
#pragma unroll
        for (int j = 0; j < 4; ++j) {
            float4v w0 = *(const float4v*)(wgate + (size_t)(h0 + j) * NEXP);
            float4v w1 = *(const float4v*)(wgate + (size_t)(h0 + j) * NEXP + 4);
            float xs = xv[j];
            acc[0] += xs * w0[0]; acc[1] += xs * w0[1];
            acc[2] += xs * w0[2]; acc[3] += xs * w0[3];
            acc[4] += xs * w1[0]; acc[5] += xs * w1[1];
            acc[6] += xs * w1[2]; acc[7] += xs * w1[3];
        }
    }
#pragma unroll
    for (int off = 32; off >= 1; off >>= 1)
#pragma unroll
        for (int e = 0; e < NEXP; ++e)
            acc[e] += __shfl_xor(acc[e], off, 64);
    if (lane == 0) {
        float m = acc[0];
#pragma unroll
        for (int e = 1; e < NEXP; ++e) m = fmaxf(m, acc[e]);
        float p[NEXP], s = 0.f;
#pragma unroll
        for (int e = 0; e < NEXP; ++e) { p[e] = __expf(acc[e] - m); s += p[e]; }
        float inv = 1.f / s;
#pragma unroll
        for (int e = 0; e < NEXP; ++e) p[e] *= inv;
        int e0 = 0; float b0 = p[0];
#pragma unroll
        for (int e = 1; e < NEXP; ++e) if (p[e] > b0) { b0 = p[e]; e0 = e; }
        int e1 = -1; float b1 = -1.f;
#pragma unroll
        for (int e = 0; e < NEXP; ++e) if (e != e0 && p[e] > b1) { b1 = p[e]; e1 = e; }
        int p0 = atomicAdd(&counts[e0], 1);
        ltok[e0 * CAP + p0] = tok; lwt[e0 * CAP + p0] = b0;
        int p1 = atomicAdd(&counts[e1], 1);
        ltok[e1 * CAP + p1] = tok; lwt[e1 * CAP + p1] = b1;
        tslot[tok * 2]     = (e0 << 16) | p0;
        tslot[tok * 2 + 1] = (e1 << 16) | p1;
    }
}

// prefix sums + compact (expert, rowtile) worklist. Sum of counts == 8192 so nwl <= 71.
__global__ void k_prefix(const int* __restrict__ counts, int* __restrict__ offs,
                         int* __restrict__ wl, int* __restrict__ nwl) {
    if (threadIdx.x == 0) {
        int s = 0;
#pragma unroll
        for (int e = 0; e < NEXP; ++e) { offs[e] = s; s += counts[e]; }
        int n = 0;
        for (int e = 0; e < NEXP; ++e)
            for (int r = 0; r * 128 < counts[e] && n < MAXWL; ++r)
                wl[n++] = (e << 8) | r;
        nwl[0] = n;
    }
}

// ---------------- GEMM1: h = silu(x@Wg) * (x@Wu), 128 rows x 64 cols per matrix ----------------
__global__ __launch_bounds__(256, 4)
void k_gemm1(const unsigned short* __restrict__ xb,    // [T][H] bf16
             const unsigned short* __restrict__ wgt,   // [E][F][H] bf16
             const unsigned short* __restrict__ wut,   // [E][F][H]
             const int* __restrict__ counts, const int* __restrict__ offs,
             const int* __restrict__ ltok,
             const int* __restrict__ wl, const int* __restrict__ nwl,
             unsigned short* __restrict__ hbuf)        // [OBR][F] bf16
{
    if ((int)blockIdx.y >= nwl[0]) return;
    const int w = wl[blockIdx.y];
    const int e = w >> 8, rowtile = w & 255;
    const int M = counts[e];
    const int ftile = blockIdx.x;  // 0..63 (64 f-cols per block)

    __shared__ __align__(16) unsigned short lA[128 * 32];   // 8 KB
    __shared__ __align__(16) unsigned short lBg[64 * 32];   // 4 KB
    __shared__ __align__(16) unsigned short lBu[64 * 32];   // 4 KB
    __shared__ int stok[128];

    const int t = threadIdx.x;
    const int wave = t >> 6, lane = t & 63;

    if (t < 128) {
        int i = rowtile * 128 + t;
        stok[t] = (i < M) ? ltok[e * CAP + i] : ltok[e * CAP];
    }
    __syncthreads();

    const int r0 = t >> 2, k8 = t & 3;
    const unsigned short* pA0 = xb + (size_t)stok[r0] * HDIM + k8 * 8;
    const unsigned short* pA1 = xb + (size_t)stok[r0 + 64] * HDIM + k8 * 8;
    const size_t wbase = (size_t)e * FDIM * HDIM + (size_t)(ftile * 64) * HDIM;
    const unsigned short* pG0 = wgt + wbase + (size_t)r0 * HDIM + k8 * 8;
    const unsigned short* pU0 = wut + wbase + (size_t)r0 * HDIM + k8 * 8;

    unsigned short* dA0 = &lA[wave * 512];
    unsigned short* dA1 = &lA[2048 + wave * 512];
    unsigned short* dG0 = &lBg[wave * 512];
    unsigned short* dU0 = &lBu[wave * 512];

    const int wm = wave >> 1, wn = wave & 1;
    const int fr = lane & 15, kg = lane >> 4;

    floatx4 accg[4][2], accu[4][2];
#pragma unroll
    for (int mi = 0; mi < 4; ++mi)
#pragma unroll
        for (int ni = 0; ni < 2; ++ni) {
            floatx4 z = {0.f, 0.f, 0.f, 0.f};
            accg[mi][ni] = z; accu[mi][ni] = z;
        }

    for (int ks = 0; ks < HDIM / 32; ++ks) {
        gl2lds16(pA0, dA0); gl2lds16(pA1, dA1);
        gl2lds16(pG0, dG0); gl2lds16(pU0, dU0);
        pA0 += 32; pA1 += 32; pG0 += 32; pU0 += 32;
        __syncthreads();
        short8 a[4], bg[2], bu[2];
#pragma unroll
        for (int mi = 0; mi < 4; ++mi)
            a[mi] = *(const short8*)&lA[(wm * 64 + mi * 16 + fr) * 32 + kg * 8];
#pragma unroll
        for (int ni = 0; ni < 2; ++ni) {
            bg[ni] = *(const short8*)&lBg[(wn * 32 + ni * 16 + fr) * 32 + kg * 8];
            bu[ni] = *(const short8*)&lBu[(wn * 32 + ni * 16 + fr) * 32 + kg * 8];
        }
#pragma unroll
        for (int mi = 0; mi < 4; ++mi)
#pragma unroll
            for (int ni = 0; ni < 2; ++ni) {
                accg[mi][ni] = __builtin_amdgcn_mfma_f32_16x16x32_bf16(a[mi], bg[ni], accg[mi][ni], 0, 0, 0);
                accu[mi][ni] = __builtin_amdgcn_mfma_f32_16x16x32_bf16(a[mi], bu[ni], accu[mi][ni], 0, 0, 0);
            }
        __syncthreads();
    }

    const int hrow0 = offs[e] + rowtile * 128;
#pragma unroll
    for (int mi = 0; mi < 4; ++mi)
#pragma unroll
        for (int ni = 0; ni < 2; ++ni) {
            int c = ftile * 64 + wn * 32 + ni * 16 + fr;
#pragma unroll
            for (int r = 0; r < 4; ++r) {
                int rr = wm * 64 + mi * 16 + kg * 4 + r;
                if (rowtile * 128 + rr < M) {
                    float g = accg[mi][ni][r];
                    float val = (g / (1.f + __expf(-g))) * accu[mi][ni][r];
                    hbuf[(size_t)(hrow0 + rr) * FDIM + c] = f2bf(val);
                }
            }
        }
}

// ---------------- GEMM2: obuf[khalf][row] = w * (h @ Wd^T), split-K=2, plain stores ----------------
__global__ __launch_bounds__(256, 2)
void k_gemm2(const unsigned short* __restrict__ hbuf,  // [OBR][F] bf16
             const unsigned short* __restrict__ wdt,   // [E][H][F] bf16
             const int* __restrict__ counts, const int* __restrict__ offs,
             const float* __restrict__ lwt,
             const int* __restrict__ wl, const int* __restrict__ nwl,
             float* __restrict__ obuf)                 // [2][OBR][H] fp32
{
    if ((int)blockIdx.y >= nwl[0]) return;
    const int w = wl[blockIdx.y];
    const int e = w >> 8, rowtile = w & 255;
    const int M = counts[e];
    const int htile = blockIdx.x;  // 0..7
    const int khalf = blockIdx.z;  // 0..1

    __shared__ __align__(16) unsigned short lA[128 * 32];
    __shared__ __align__(16) unsigned short lB[128 * 32];
    __shared__ float swt[128];

    const int t = threadIdx.x;
    const int wave = t >> 6, lane = t & 63;

    if (t < 128) {
        int i = rowtile * 128 + t;
        swt[t] = (i < M) ? lwt[e * CAP + i] : 0.f;
    }

    const int row0 = offs[e] + rowtile * 128;
    const int r0 = t >> 2, k8 = t & 3;
    const int kofs = khalf * (FDIM / 2);
    const unsigned short* pA0 = hbuf + (size_t)(row0 + r0) * FDIM + kofs + k8 * 8;
    const unsigned short* pA1 = hbuf + (size_t)(row0 + 64 + r0) * FDIM + kofs + k8 * 8;
    const size_t wb = (size_t)e * HDIM * FDIM + (size_t)(htile * 128) * FDIM;
    const unsigned short* pB0 = wdt + wb + (size_t)r0 * FDIM + kofs + k8 * 8;
    const unsigned short* pB1 = wdt + wb + (size_t)(64 + r0) * FDIM + kofs + k8 * 8;

    unsigned short* dA0 = &lA[wave * 512];
    unsigned short* dA1 = &lA[2048 + wave * 512];
    unsigned short* dB0 = &lB[wave * 512];
    unsigned short* dB1 = &lB[2048 + wave * 512];

    const int wm = wave >> 1, wn = wave & 1;
    const int fr = lane & 15, kg = lane >> 4;

    floatx4 acc[4][4];
#pragma unroll
    for (int mi = 0; mi < 4; ++mi)
#pragma unroll
        for (int ni = 0; ni < 4; ++ni) {
            floatx4 z = {0.f, 0.f, 0.f, 0.f};
            acc[mi][ni] = z;
        }

    for (int ks = 0; ks < FDIM / 64; ++ks) {   // 64 steps of BK=32 over this K-half
        gl2lds16(pA0, dA0); gl2lds16(pA1, dA1);
        gl2lds16(pB0, dB0); gl2lds16(pB1, dB1);
        pA0 += 32; pA1 += 32; pB0 += 32; pB1 += 32;
        __syncthreads();
        short8 a[4], b[4];
#pragma unroll
        for (int mi = 0; mi < 4; ++mi)
            a[mi] = *(const short8*)&lA[(wm * 64 + mi * 16 + fr) * 32 + kg * 8];
#pragma unroll
        for (int ni = 0; ni < 4; ++ni)
            b[ni] = *(const short8*)&lB[(wn * 64 + ni * 16 + fr) * 32 + kg * 8];
#pragma unroll
        for (int mi = 0; mi < 4; ++mi)
#pragma unroll
            for (int ni = 0; ni < 4; ++ni)
                acc[mi][ni] = __builtin_amdgcn_mfma_f32_16x16x32_bf16(a[mi], b[ni], acc[mi][ni], 0, 0, 0);
        __syncthreads();
    }

    float* ob = obuf + (size_t)khalf * OBR * HDIM;
#pragma unroll
    for (int mi = 0; mi < 4; ++mi)
#pragma unroll
        for (int ni = 0; ni < 4; ++ni) {
            int c = htile * 128 + wn * 64 + ni * 16 + fr;
#pragma unroll
            for (int r = 0; r < 4; ++r) {
                int rr = wm * 64 + mi * 16 + kg * 4 + r;
                if (rowtile * 128 + rr < M)
                    ob[(size_t)(row0 + rr) * HDIM + c] = acc[mi][ni][r] * swt[rr];
            }
        }
}

// ---------------- combine: out[tok] = sum over 2 slots x 2 k-halves ----------------
__global__ void k_combine(const float* __restrict__ obuf, const int* __restrict__ tslot,
                          const int* __restrict__ offs, float* __restrict__ out) {
    int gid = blockIdx.x * 256 + threadIdx.x;
    int tok = gid >> 8;           // 256 threads per token
    int c = (gid & 255) * 4;
    int s0 = tslot[tok * 2], s1 = tslot[tok * 2 + 1];
    size_t r0 = (size_t)(offs[s0 >> 16] + (s0 & 0xFFFF));
    size_t r1 = (size_t)(offs[s1 >> 16] + (s1 & 0xFFFF));
    float4v v00 = *(const float4v*)(obuf + r0 * HDIM + c);
    float4v v01 = *(const float4v*)(obuf + ((size_t)OBR + r0) * HDIM + c);
    float4v v10 = *(const float4v*)(obuf + r1 * HDIM + c);
    float4v v11 = *(const float4v*)(obuf + ((size_t)OBR + r1) * HDIM + c);
    float4v s = v00 + v01 + v10 + v11;
    *(float4v*)(out + (size_t)tok * HDIM + c) = s;
}

extern "C" void kernel_launch(void* const* d_in, const int* in_sizes, int n_in,
                              void* d_out, int out_size, void* d_ws, size_t ws_size,
                              hipStream_t stream) {
    const float* x     = (const float*)d_in[0];  // [4096][1024]
    const float* wgate = (const float*)d_in[1];  // [1024][8]
    const float* wg    = (const float*)d_in[2];  // [8][1024][4096]
    const float* wu    = (const float*)d_in[3];  // [8][1024][4096]
    const float* wd    = (const float*)d_in[4];  // [8][4096][1024]
    float* out = (float*)d_out;

    char* ws = (char*)d_ws;
    size_t off = 0;
    unsigned short* xb  = (unsigned short*)(ws + off); off += (size_t)T_TOK * HDIM * 2;
    unsigned short* wgt = (unsigned short*)(ws + off); off += (size_t)NEXP * FDIM * HDIM * 2;
    unsigned short* wut = (unsigned short*)(ws + off); off += (size_t)NEXP * FDIM * HDIM * 2;
    unsigned short* wdt = (unsigned short*)(ws + off); off += (size_t)NEXP * HDIM * FDIM * 2;
    unsigned short* hbuf= (unsigned short*)(ws + off); off += (size_t)OBR * FDIM * 2;
    int*   ltok   = (int*)(ws + off);   off += (size_t)NEXP * CAP * 4;
    float* lwt    = (float*)(ws + off); off += (size_t)NEXP * CAP * 4;
    int*   tslot  = (int*)(ws + off);   off += (size_t)T_TOK * 2 * 4;
    int*   counts = (int*)(ws + off);   off += 256;
    int*   offs   = (int*)(ws + off);   off += 256;
    int*   wl     = (int*)(ws + off);   off += MAXWL * 4;
    int*   nwl    = (int*)(ws + off);   off += 256;
    // obuf aliases wgt+wut (dead after gemm1): 2*OBR*HDIM*4 = 68 MB < 134 MB
    float* obuf = (float*)wgt;

    hipMemsetAsync(counts, 0, 32, stream);

    k_router<<<T_TOK / 4, 256, 0, stream>>>(x, wgate, xb, counts, ltok, lwt, tslot);
    k_transpose_cast<<<dim3(FDIM / 64, HDIM / 64, NEXP), 256, 0, stream>>>(wg, wgt, HDIM, FDIM);
    k_transpose_cast<<<dim3(FDIM / 64, HDIM / 64, NEXP), 256, 0, stream>>>(wu, wut, HDIM, FDIM);
    k_transpose_cast<<<dim3(HDIM / 64, FDIM / 64, NEXP), 256, 0, stream>>>(wd, wdt, FDIM, HDIM);
    k_prefix<<<1, 64, 0, stream>>>(counts, offs, wl, nwl);
    k_gemm1<<<dim3(FDIM / 64, 72), 256, 0, stream>>>(xb, wgt, wut, counts, offs, ltok, wl, nwl, hbuf);
    k_gemm2<<<dim3(HDIM / 128, 72, 2), 256, 0, stream>>>(hbuf, wdt, counts, offs, lwt, wl, nwl, obuf);
    k_combine<<<T_TOK * HDIM / 1024, 256, 0, stream>>>(obuf, tslot, offs, out);
}